// Round 16
// baseline (179.207 us; speedup 1.0000x reference)
//
#include <hip/hip_runtime.h>
#include <math.h>

// ---------------------------------------------------------------------------
// MultiHeadAttention: q/k/v = 1x1conv(x), flash attention, out [B,256,56,56] f32
// B=4, Cin=Cout=256, H=W=56 (N=3136), heads=8, hd=32.
// xbT[b][n][c] bf16 -> proj GEMM (MFMA 16x16x32 bf16) -> Q,K [bh][n][32],
// V transposed [bh][32][n] -> attn: QK^T(swapped) -> exp2 -> P via LDS -> PV.
// R16: BARRIER-FREE k_attn. Each wave stages its OWN 8KB K/V slot (K and V
// fragment reads never depended on wid; sharing only existed to economize
// staging, and it forced a 4-wave convoy barrier every iteration). Sync is
// per-wave: vmcnt(0)+sched_barrier before consume (rule-18), lgkmcnt(0)
// fence before restage. NO __syncthreads in the loop -> waves drift and
// cross-hide stalls (m114); setprio now acts on independent waves (m191).
// Chunk->source formula is the R14-PASSING parameterization (ss replaces
// wid). P round-trip, fences, ones-MFMA lsum, XCD grid: verbatim R10/R11.
// log2(e)/sqrt(32) folded into Wq/bq; direct exp2 (scores bounded, no max).
// ---------------------------------------------------------------------------

#define NB   4
#define CIN  256
#define NPIX 3136
#define NH   8
#define HD   32
#define QSC  0.25503837897544295f   /* log2(e)/sqrt(32) */

typedef float          f32x4  __attribute__((ext_vector_type(4)));
typedef short          bf16x8 __attribute__((ext_vector_type(8)));
typedef unsigned int   u32x4  __attribute__((ext_vector_type(4)));
typedef unsigned int   u32x2  __attribute__((ext_vector_type(2)));
typedef unsigned short u16x4  __attribute__((ext_vector_type(4)));

static __device__ __forceinline__ unsigned short f2bf(float f) {
  union { float f; unsigned u; } v; v.f = f;
  return (unsigned short)((v.u + 0x7fffu + ((v.u >> 16) & 1u)) >> 16);  // RTNE
}

// raw v_exp_f32 (R15-verified: same perf as builtin; keep the pinned form)
static __device__ __forceinline__ float fast_exp2(float x) {
  float r;
  asm("v_exp_f32 %0, %1" : "=v"(r) : "v"(x));
  return r;
}

// pack two f32 -> one dword of 2 bf16 (order verified by R3/R7/R10 pass)
static __device__ __forceinline__ unsigned cvt_pk_bf16(float lo, float hi) {
  unsigned r;
  asm("v_cvt_pk_bf16_f32 %0, %1, %2" : "=v"(r) : "v"(lo), "v"(hi));
  return r;
}

// async global->LDS, 16B per lane. LDS dest must be wave-uniform base + lane*16.
static __device__ __forceinline__ void gload_lds16(const void* g, void* l) {
  __builtin_amdgcn_global_load_lds(
      (__attribute__((address_space(1))) const void*)g,
      (__attribute__((address_space(3))) void*)l, 16, 0, 0);
}

static __device__ __forceinline__ bf16x8 lds_frag16(const unsigned char* p) {
  u32x4 u = *(const u32x4*)p;
  return __builtin_bit_cast(bf16x8, u);
}

// ---------------------------------------------------------------------------
// k_xpose: x[b][c][n] f32 -> xbT[b][n][c] bf16.  grid (49, 4, 4), 256 thr.
// ---------------------------------------------------------------------------
__global__ __launch_bounds__(256) void k_xpose(const float* __restrict__ x,
                                               unsigned short* __restrict__ xbT) {
  __shared__ unsigned short tile[64][66];
  const int n0 = blockIdx.x * 64, c0 = blockIdx.y * 64, b = blockIdx.z;
  const int t = threadIdx.x;
  const int cl = t >> 4, nl = (t & 15) * 4;
#pragma unroll
  for (int rep = 0; rep < 4; ++rep) {
    const int c = cl + rep * 16;
    f32x4 v = *(const f32x4*)(x + ((size_t)(b * CIN + c0 + c)) * NPIX + n0 + nl);
    tile[nl + 0][c] = f2bf(v.x);
    tile[nl + 1][c] = f2bf(v.y);
    tile[nl + 2][c] = f2bf(v.z);
    tile[nl + 3][c] = f2bf(v.w);
  }
  __syncthreads();
  const int nr = t >> 2, co = (t & 3) * 16;
  unsigned pw[8];
#pragma unroll
  for (int j = 0; j < 8; ++j)
    pw[j] = (unsigned)tile[nr][co + 2 * j] | ((unsigned)tile[nr][co + 2 * j + 1] << 16);
  unsigned short* dst = xbT + ((size_t)(b * NPIX + n0 + nr)) * 256 + c0 + co;
  u32x4 lo = {pw[0], pw[1], pw[2], pw[3]};
  u32x4 hi = {pw[4], pw[5], pw[6], pw[7]};
  *(u32x4*)dst = lo;
  *(u32x4*)(dst + 8) = hi;
}

// ---------------------------------------------------------------------------
// k_wconv: wq/wk/wv f32 -> wb bf16 [mat][o][c]; wq scaled by QSC. grid 768.
// ---------------------------------------------------------------------------
__global__ __launch_bounds__(256) void k_wconv(const float* __restrict__ wq,
                                               const float* __restrict__ wk,
                                               const float* __restrict__ wv,
                                               unsigned short* __restrict__ wb) {
  const int i = blockIdx.x * 256 + threadIdx.x;   // 3*65536 total
  const int mat = i >> 16, idx = i & 65535;
  const float* w = (mat == 0) ? wq : (mat == 1 ? wk : wv);
  const float s = (mat == 0) ? QSC : 1.0f;
  wb[i] = f2bf(w[idx] * s);
}

// ---------------------------------------------------------------------------
// k_proj: per (mat,b,ntile): C[256 o][64 n] = W*XbT^T + bias.
// 4 waves; wave owns mtiles {w, w+4, w+8, w+12}; 8 K-steps of 32.
// LDS frag-major chunks staged with global_load_lds; all ds_read_b128 linear.
// Q,K -> [bh][n][32] bf16 ; V -> [bh][32][n] bf16 (pre-transposed for attn).
// grid (49, 12): y = mat*4 + b.
// ---------------------------------------------------------------------------
__global__ __launch_bounds__(256) void k_proj(
    const unsigned short* __restrict__ xbT, const unsigned short* __restrict__ wb,
    const float* __restrict__ bq, const float* __restrict__ bk,
    const float* __restrict__ bv,
    unsigned short* __restrict__ qws, unsigned short* __restrict__ kws,
    unsigned short* __restrict__ vtws) {
  __shared__ alignas(16) unsigned char lds[20480];  // W frags 16KB @0, X frags 4KB @16384
  const int b = blockIdx.y & 3, mat = blockIdx.y >> 2;
  const int n0 = blockIdx.x * 64;
  const int t = threadIdx.x, l = t & 63, wid = t >> 6, g = l >> 4, q = l & 15;
  const unsigned short* wmat = wb + mat * (256 * 256);

  f32x4 acc[4][4] = {};  // [r(mtile)][nt]

  for (int ks = 0; ks < 8; ++ks) {
#pragma unroll
    for (int r = 0; r < 4; ++r) {
      const unsigned short* src = wmat + ((wid + 4 * r) * 16 + q) * 256 + ks * 32 + g * 8;
      gload_lds16(src, lds + (r * 256 + t) * 16);
    }
    gload_lds16(xbT + ((size_t)(b * NPIX + n0 + wid * 16 + q)) * 256 + ks * 32 + g * 8,
                lds + 16384 + t * 16);
    __syncthreads();

    bf16x8 wa[4], xf[4];
#pragma unroll
    for (int r = 0; r < 4; ++r) wa[r] = lds_frag16(lds + (r * 256 + wid * 64 + l) * 16);
#pragma unroll
    for (int nt = 0; nt < 4; ++nt) xf[nt] = lds_frag16(lds + 16384 + (nt * 64 + l) * 16);
#pragma unroll
    for (int r = 0; r < 4; ++r)
#pragma unroll
      for (int nt = 0; nt < 4; ++nt)
        acc[r][nt] = __builtin_amdgcn_mfma_f32_16x16x32_bf16(wa[r], xf[nt], acc[r][nt], 0, 0, 0);
    __syncthreads();
  }

  const float* bias = (mat == 0) ? bq : (mat == 1 ? bk : bv);
  const float bsc = (mat == 0) ? QSC : 1.0f;
#pragma unroll
  for (int r = 0; r < 4; ++r) {
    const int ob = (wid + 4 * r) * 16 + g * 4;  // o = ob + reg
    const int h = ob >> 5, d0 = ob & 31;
    const float b0 = bias[ob + 0] * bsc, b1 = bias[ob + 1] * bsc;
    const float b2 = bias[ob + 2] * bsc, b3 = bias[ob + 3] * bsc;
#pragma unroll
    for (int nt = 0; nt < 4; ++nt) {
      const int n = n0 + nt * 16 + q;
      f32x4 a = acc[r][nt];
      if (mat < 2) {
        unsigned short* dst = (mat == 0) ? qws : kws;
        u16x4 pk = {f2bf(a.x + b0), f2bf(a.y + b1), f2bf(a.z + b2), f2bf(a.w + b3)};
        *(u16x4*)(dst + ((size_t)((b * NH + h) * NPIX + n)) * HD + d0) = pk;
      } else {
        unsigned short* vr = vtws + ((size_t)((b * NH + h) * HD + d0)) * NPIX + n;
        vr[0] = f2bf(a.x + b0);
        vr[(size_t)NPIX] = f2bf(a.y + b1);
        vr[(size_t)2 * NPIX] = f2bf(a.z + b2);
        vr[(size_t)3 * NPIX] = f2bf(a.w + b3);
      }
    }
  }
}

// ---------------------------------------------------------------------------
// k_attn: 1D grid 800 blocks, XCD decode (R11-verified). 256 thr = 4 waves;
// wave wid owns TWO 16-q tiles (rows q0+wid*32+q, +16). BARRIER-FREE:
// each wave stages its own 8KB K/V slot (K@kvb, V@kvb+4096) with 8
// gload_lds (chunk formulas = R14-passing parameterization, ss = 0..3):
//   K op ss: row kt*64 + ss*16 + q, dwords g*8..   -> kvb + ss*1024 + l*16
//   V op ss: VT row (ss>>1)*16+q, col kt*64+(ss&1)*32+g*8 -> +4096+ss*1024
// Per-wave sync: vmcnt(0)+sched_barrier before consume; lgkmcnt(0)+
// sched_barrier after PV (frag reads retired) before restaging the slot.
// P round-trip + fence, ones-MFMA lsum, output: verbatim R10/R11-passing.
// LDS: 4 x 8KB KV @0; P 16KB @32768 -> 48KB, 3 blocks/CU (12 waves/CU).
// ---------------------------------------------------------------------------
__global__ __launch_bounds__(256) void k_attn(
    const unsigned short* __restrict__ qws, const unsigned short* __restrict__ kws,
    const unsigned short* __restrict__ vtws, float* __restrict__ out) {
  __shared__ alignas(16) unsigned char lds[49152];
  const int bid = blockIdx.x;
  const int xcd = bid & 7, inner = bid >> 3;
  const int qt = inner % 25;
  const int bh = 8 * (inner / 25) + xcd;
  const int q0 = qt * 128;
  const int t = threadIdx.x, l = t & 63, wid = t >> 6, g = l >> 4, q = l & 15;

  const int nA = q0 + wid * 32 + q;     // q-tile A row
  const int nB = nA + 16;               // q-tile B row
  const int rowA = (nA < NPIX) ? nA : (NPIX - 1);
  const int rowB = (nB < NPIX) ? nB : (NPIX - 1);

  u32x4 quA = *(const u32x4*)(qws + ((size_t)(bh * NPIX + rowA)) * HD + g * 8);
  u32x4 quB = *(const u32x4*)(qws + ((size_t)(bh * NPIX + rowB)) * HD + g * 8);
  const bf16x8 qfA = __builtin_bit_cast(bf16x8, quA);
  const bf16x8 qfB = __builtin_bit_cast(bf16x8, quB);
  const u32x4 onesu = {0x3F803F80u, 0x3F803F80u, 0x3F803F80u, 0x3F803F80u};
  const bf16x8 onesf = __builtin_bit_cast(bf16x8, onesu);  // bf16 1.0 x8
  const f32x4 zero4 = {0.f, 0.f, 0.f, 0.f};

  f32x4 oA0 = zero4, oA1 = zero4, oB0 = zero4, oB1 = zero4;
  f32x4 sumA = zero4, sumB = zero4;

  unsigned char* const kvb = lds + wid * 8192;            // K @+0, V @+4096
  unsigned char* const pbaseA = lds + 32768 + wid * 4096;
  unsigned char* const pbaseB = pbaseA + 2048;

  // per-ss staging base pointers (R14-passing chunk formulas, ss in place of wid)
  const unsigned short* kp[4];
  const unsigned short* vp[4];
#pragma unroll
  for (int ss = 0; ss < 4; ++ss) {
    kp[ss] = kws + ((size_t)(bh * NPIX + ss * 16 + q)) * HD + g * 8;
    vp[ss] = vtws + ((size_t)(bh * HD + (ss >> 1) * 16 + q)) * NPIX + (ss & 1) * 32 + g * 8;
  }

#define STG(kt_)                                                             \
  do {                                                                       \
    _Pragma("unroll")                                                        \
    for (int ss = 0; ss < 4; ++ss) {                                         \
      gload_lds16(kp[ss] + (size_t)(kt_) * 64 * HD, kvb + ss * 1024 + l * 16); \
      gload_lds16(vp[ss] + (size_t)(kt_) * 64, kvb + 4096 + ss * 1024 + l * 16); \
    }                                                                        \
  } while (0)

  STG(0);

  for (int kt = 0; kt < 49; ++kt) {
    // wait for this wave's staged slot (gload_lds tracked by vmcnt); forbid
    // hoisting the ds_reads above the wait (rule-18 pattern).
    asm volatile("s_waitcnt vmcnt(0)" ::: "memory");
    __builtin_amdgcn_sched_barrier(0);

    const unsigned char* kb = kvb;
    const unsigned char* vb = kvb + 4096;

    // QK^T for both q-tiles from ONE set of K fragment reads
    f32x4 sA[4], sB[4];
    __builtin_amdgcn_s_setprio(1);
#pragma unroll
    for (int jj = 0; jj < 4; ++jj) {
      bf16x8 kf = lds_frag16(kb + (jj * 64 + l) * 16);
      sA[jj] = __builtin_amdgcn_mfma_f32_16x16x32_bf16(kf, qfA, zero4, 0, 0, 0);
      sB[jj] = __builtin_amdgcn_mfma_f32_16x16x32_bf16(kf, qfB, zero4, 0, 0, 0);
    }
    __builtin_amdgcn_s_setprio(0);

    // p = exp2(s); pack; write P chunks (per-wave region)
    {
      unsigned pw[8];
#pragma unroll
      for (int jj = 0; jj < 4; ++jj) {
#pragma unroll
        for (int rp = 0; rp < 2; ++rp) {
          float p0 = fast_exp2(sA[jj][2 * rp + 0]);
          float p1 = fast_exp2(sA[jj][2 * rp + 1]);
          pw[jj * 2 + rp] = cvt_pk_bf16(p0, p1);
        }
      }
      u32x4 c0 = {pw[0], pw[1], pw[2], pw[3]};
      u32x4 c1 = {pw[4], pw[5], pw[6], pw[7]};
      *(u32x4*)(pbaseA + l * 16) = c0;
      *(u32x4*)(pbaseA + 1024 + l * 16) = c1;
    }
    {
      unsigned pw[8];
#pragma unroll
      for (int jj = 0; jj < 4; ++jj) {
#pragma unroll
        for (int rp = 0; rp < 2; ++rp) {
          float p0 = fast_exp2(sB[jj][2 * rp + 0]);
          float p1 = fast_exp2(sB[jj][2 * rp + 1]);
          pw[jj * 2 + rp] = cvt_pk_bf16(p0, p1);
        }
      }
      u32x4 c0 = {pw[0], pw[1], pw[2], pw[3]};
      u32x4 c1 = {pw[4], pw[5], pw[6], pw[7]};
      *(u32x4*)(pbaseB + l * 16) = c0;
      *(u32x4*)(pbaseB + 1024 + l * 16) = c1;
    }

    // HARD ORDER: drain the P ds_writes; forbid hoisting the gathers (R7).
    asm volatile("s_waitcnt lgkmcnt(0)" ::: "memory");
    __builtin_amdgcn_sched_barrier(0);

    // PV for both q-tiles from ONE set of V fragment reads + ones column-sums
#pragma unroll
    for (int c = 0; c < 2; ++c) {
      bf16x8 v0 = lds_frag16(vb + (c * 64 + l) * 16);          // d 0..15
      bf16x8 v1 = lds_frag16(vb + (128 + c * 64 + l) * 16);    // d 16..31

      const unsigned char* pA = pbaseA + c * 1024 + q * 16 + (g & 2) * 4;
      u32x2 alo = *(const u32x2*)(pA + ((2 * g) & 3) * 256);
      u32x2 ahi = *(const u32x2*)(pA + ((2 * g + 1) & 3) * 256);
      u32x4 au = {alo.x, alo.y, ahi.x, ahi.y};
      bf16x8 pfA = __builtin_bit_cast(bf16x8, au);

      const unsigned char* pB = pbaseB + c * 1024 + q * 16 + (g & 2) * 4;
      u32x2 blo = *(const u32x2*)(pB + ((2 * g) & 3) * 256);
      u32x2 bhi = *(const u32x2*)(pB + ((2 * g + 1) & 3) * 256);
      u32x4 bu = {blo.x, blo.y, bhi.x, bhi.y};
      bf16x8 pfB = __builtin_bit_cast(bf16x8, bu);

      __builtin_amdgcn_s_setprio(1);
      oA0 = __builtin_amdgcn_mfma_f32_16x16x32_bf16(v0, pfA, oA0, 0, 0, 0);
      oA1 = __builtin_amdgcn_mfma_f32_16x16x32_bf16(v1, pfA, oA1, 0, 0, 0);
      sumA = __builtin_amdgcn_mfma_f32_16x16x32_bf16(onesf, pfA, sumA, 0, 0, 0);
      oB0 = __builtin_amdgcn_mfma_f32_16x16x32_bf16(v0, pfB, oB0, 0, 0, 0);
      oB1 = __builtin_amdgcn_mfma_f32_16x16x32_bf16(v1, pfB, oB1, 0, 0, 0);
      sumB = __builtin_amdgcn_mfma_f32_16x16x32_bf16(onesf, pfB, sumB, 0, 0, 0);
      __builtin_amdgcn_s_setprio(0);
    }

    // drain ALL this wave's ds_reads (kf/v/p retired into regs) before the
    // slot is overwritten by the next stage; pin order (rule-18 pattern).
    asm volatile("s_waitcnt lgkmcnt(0)" ::: "memory");
    __builtin_amdgcn_sched_barrier(0);

    if (kt < 48) STG(kt + 1);
  }
#undef STG

  // sumX[0] = full-key sum for q-column q (all rows of ones*P identical)
  if (nA < NPIX) {
    const float inv = 1.0f / sumA[0];
    float* ob = out + (size_t)(bh * HD) * NPIX + nA;
#pragma unroll
    for (int r = 0; r < 4; ++r) {
      ob[(size_t)(g * 4 + r) * NPIX] = oA0[r] * inv;
      ob[(size_t)(16 + g * 4 + r) * NPIX] = oA1[r] * inv;
    }
  }
  if (nB < NPIX) {
    const float inv = 1.0f / sumB[0];
    float* ob = out + (size_t)(bh * HD) * NPIX + nB;
#pragma unroll
    for (int r = 0; r < 4; ++r) {
      ob[(size_t)(g * 4 + r) * NPIX] = oB0[r] * inv;
      ob[(size_t)(16 + g * 4 + r) * NPIX] = oB1[r] * inv;
    }
  }
}

// ---------------------------------------------------------------------------
extern "C" void kernel_launch(void* const* d_in, const int* in_sizes, int n_in,
                              void* d_out, int out_size, void* d_ws, size_t ws_size,
                              hipStream_t stream) {
  const float* x  = (const float*)d_in[0];
  const float* wq = (const float*)d_in[1];
  const float* bq = (const float*)d_in[2];
  const float* wk = (const float*)d_in[3];
  const float* bk = (const float*)d_in[4];
  const float* wv = (const float*)d_in[5];
  const float* bv = (const float*)d_in[6];
  float* out = (float*)d_out;

  unsigned char* ws = (unsigned char*)d_ws;
  unsigned short* xbT  = (unsigned short*)(ws);             // 6,422,528 B
  unsigned short* wb   = (unsigned short*)(ws + 6422528);   //   393,216 B
  unsigned short* qws  = (unsigned short*)(ws + 6815744);   // 6,422,528 B
  unsigned short* kws  = (unsigned short*)(ws + 13238272);  // 6,422,528 B
  unsigned short* vtws = (unsigned short*)(ws + 19660800);  // 6,422,528 B

  k_xpose<<<dim3(49, 4, 4), 256, 0, stream>>>(x, xbT);
  k_wconv<<<dim3(768), 256, 0, stream>>>(wq, wk, wv, wb);
  k_proj<<<dim3(49, 12), 256, 0, stream>>>(xbT, wb, bq, bk, bv, qws, kws, vtws);
  k_attn<<<dim3(800), 256, 0, stream>>>(qws, kws, vtws, out);
}

// Round 17
// 166.751 us; speedup vs baseline: 1.0747x; 1.0747x over previous
//
#include <hip/hip_runtime.h>
#include <math.h>

// ---------------------------------------------------------------------------
// MultiHeadAttention: q/k/v = 1x1conv(x), flash attention, out [B,256,56,56] f32
// B=4, Cin=Cout=256, H=W=56 (N=3136), heads=8, hd=32.
// xbT[b][n][c] bf16 -> proj GEMM (MFMA 16x16x32 bf16) -> Q,K [bh][n][32],
// V transposed [bh][32][n] -> attn: QK^T(swapped) -> exp2 -> P via LDS -> PV.
// R17: NO K/V LDS STAGING. K/V are L2-resident (9.4MB, R11) -- staging
// L2-fit data is pure overhead (guide common-mistake #7, m169). Fragment
// reads become DIRECT global loads (dense/coalesced by construction of the
// frag-major layout): kf[jj] = kws[(bh*N + kt*64 + jj*16 + q)*32 + g*8],
// vf[h][c] = vtws[(bh*32 + h*16 + q)*N + kt*64 + c*32 + g*8] -- mechanical
// composition of the R14-passing chunk formulas with R3-passing frag ids.
// Ping-pong register prefetch one tile ahead. NO __syncthreads in loop
// (P is wave-private; LDS in-order per wave; write->read fence R7-proven;
// loop-end sched_barrier(0) pins read->write order against TBAA hoisting).
// lsum via ones-MFMA (R10-verified). XCD grid (R11-verified). exp2 direct.
// ---------------------------------------------------------------------------

#define NB   4
#define CIN  256
#define NPIX 3136
#define NH   8
#define HD   32
#define QSC  0.25503837897544295f   /* log2(e)/sqrt(32) */

typedef float          f32x4  __attribute__((ext_vector_type(4)));
typedef short          bf16x8 __attribute__((ext_vector_type(8)));
typedef unsigned int   u32x4  __attribute__((ext_vector_type(4)));
typedef unsigned int   u32x2  __attribute__((ext_vector_type(2)));
typedef unsigned short u16x4  __attribute__((ext_vector_type(4)));

static __device__ __forceinline__ unsigned short f2bf(float f) {
  union { float f; unsigned u; } v; v.f = f;
  return (unsigned short)((v.u + 0x7fffu + ((v.u >> 16) & 1u)) >> 16);  // RTNE
}

// raw v_exp_f32 (R15-verified)
static __device__ __forceinline__ float fast_exp2(float x) {
  float r;
  asm("v_exp_f32 %0, %1" : "=v"(r) : "v"(x));
  return r;
}

// pack two f32 -> one dword of 2 bf16 (order verified by R3/R7/R10 pass)
static __device__ __forceinline__ unsigned cvt_pk_bf16(float lo, float hi) {
  unsigned r;
  asm("v_cvt_pk_bf16_f32 %0, %1, %2" : "=v"(r) : "v"(lo), "v"(hi));
  return r;
}

// async global->LDS, 16B per lane (still used by k_proj).
static __device__ __forceinline__ void gload_lds16(const void* g, void* l) {
  __builtin_amdgcn_global_load_lds(
      (__attribute__((address_space(1))) const void*)g,
      (__attribute__((address_space(3))) void*)l, 16, 0, 0);
}

static __device__ __forceinline__ bf16x8 lds_frag16(const unsigned char* p) {
  u32x4 u = *(const u32x4*)p;
  return __builtin_bit_cast(bf16x8, u);
}

// ---------------------------------------------------------------------------
// k_xpose: x[b][c][n] f32 -> xbT[b][n][c] bf16.  grid (49, 4, 4), 256 thr.
// ---------------------------------------------------------------------------
__global__ __launch_bounds__(256) void k_xpose(const float* __restrict__ x,
                                               unsigned short* __restrict__ xbT) {
  __shared__ unsigned short tile[64][66];
  const int n0 = blockIdx.x * 64, c0 = blockIdx.y * 64, b = blockIdx.z;
  const int t = threadIdx.x;
  const int cl = t >> 4, nl = (t & 15) * 4;
#pragma unroll
  for (int rep = 0; rep < 4; ++rep) {
    const int c = cl + rep * 16;
    f32x4 v = *(const f32x4*)(x + ((size_t)(b * CIN + c0 + c)) * NPIX + n0 + nl);
    tile[nl + 0][c] = f2bf(v.x);
    tile[nl + 1][c] = f2bf(v.y);
    tile[nl + 2][c] = f2bf(v.z);
    tile[nl + 3][c] = f2bf(v.w);
  }
  __syncthreads();
  const int nr = t >> 2, co = (t & 3) * 16;
  unsigned pw[8];
#pragma unroll
  for (int j = 0; j < 8; ++j)
    pw[j] = (unsigned)tile[nr][co + 2 * j] | ((unsigned)tile[nr][co + 2 * j + 1] << 16);
  unsigned short* dst = xbT + ((size_t)(b * NPIX + n0 + nr)) * 256 + c0 + co;
  u32x4 lo = {pw[0], pw[1], pw[2], pw[3]};
  u32x4 hi = {pw[4], pw[5], pw[6], pw[7]};
  *(u32x4*)dst = lo;
  *(u32x4*)(dst + 8) = hi;
}

// ---------------------------------------------------------------------------
// k_wconv: wq/wk/wv f32 -> wb bf16 [mat][o][c]; wq scaled by QSC. grid 768.
// ---------------------------------------------------------------------------
__global__ __launch_bounds__(256) void k_wconv(const float* __restrict__ wq,
                                               const float* __restrict__ wk,
                                               const float* __restrict__ wv,
                                               unsigned short* __restrict__ wb) {
  const int i = blockIdx.x * 256 + threadIdx.x;   // 3*65536 total
  const int mat = i >> 16, idx = i & 65535;
  const float* w = (mat == 0) ? wq : (mat == 1 ? wk : wv);
  const float s = (mat == 0) ? QSC : 1.0f;
  wb[i] = f2bf(w[idx] * s);
}

// ---------------------------------------------------------------------------
// k_proj: per (mat,b,ntile): C[256 o][64 n] = W*XbT^T + bias.
// 4 waves; wave owns mtiles {w, w+4, w+8, w+12}; 8 K-steps of 32.
// LDS frag-major chunks staged with global_load_lds; all ds_read_b128 linear.
// Q,K -> [bh][n][32] bf16 ; V -> [bh][32][n] bf16 (pre-transposed for attn).
// grid (49, 12): y = mat*4 + b.
// ---------------------------------------------------------------------------
__global__ __launch_bounds__(256) void k_proj(
    const unsigned short* __restrict__ xbT, const unsigned short* __restrict__ wb,
    const float* __restrict__ bq, const float* __restrict__ bk,
    const float* __restrict__ bv,
    unsigned short* __restrict__ qws, unsigned short* __restrict__ kws,
    unsigned short* __restrict__ vtws) {
  __shared__ alignas(16) unsigned char lds[20480];  // W frags 16KB @0, X frags 4KB @16384
  const int b = blockIdx.y & 3, mat = blockIdx.y >> 2;
  const int n0 = blockIdx.x * 64;
  const int t = threadIdx.x, l = t & 63, wid = t >> 6, g = l >> 4, q = l & 15;
  const unsigned short* wmat = wb + mat * (256 * 256);

  f32x4 acc[4][4] = {};  // [r(mtile)][nt]

  for (int ks = 0; ks < 8; ++ks) {
#pragma unroll
    for (int r = 0; r < 4; ++r) {
      const unsigned short* src = wmat + ((wid + 4 * r) * 16 + q) * 256 + ks * 32 + g * 8;
      gload_lds16(src, lds + (r * 256 + t) * 16);
    }
    gload_lds16(xbT + ((size_t)(b * NPIX + n0 + wid * 16 + q)) * 256 + ks * 32 + g * 8,
                lds + 16384 + t * 16);
    __syncthreads();

    bf16x8 wa[4], xf[4];
#pragma unroll
    for (int r = 0; r < 4; ++r) wa[r] = lds_frag16(lds + (r * 256 + wid * 64 + l) * 16);
#pragma unroll
    for (int nt = 0; nt < 4; ++nt) xf[nt] = lds_frag16(lds + 16384 + (nt * 64 + l) * 16);
#pragma unroll
    for (int r = 0; r < 4; ++r)
#pragma unroll
      for (int nt = 0; nt < 4; ++nt)
        acc[r][nt] = __builtin_amdgcn_mfma_f32_16x16x32_bf16(wa[r], xf[nt], acc[r][nt], 0, 0, 0);
    __syncthreads();
  }

  const float* bias = (mat == 0) ? bq : (mat == 1 ? bk : bv);
  const float bsc = (mat == 0) ? QSC : 1.0f;
#pragma unroll
  for (int r = 0; r < 4; ++r) {
    const int ob = (wid + 4 * r) * 16 + g * 4;  // o = ob + reg
    const int h = ob >> 5, d0 = ob & 31;
    const float b0 = bias[ob + 0] * bsc, b1 = bias[ob + 1] * bsc;
    const float b2 = bias[ob + 2] * bsc, b3 = bias[ob + 3] * bsc;
#pragma unroll
    for (int nt = 0; nt < 4; ++nt) {
      const int n = n0 + nt * 16 + q;
      f32x4 a = acc[r][nt];
      if (mat < 2) {
        unsigned short* dst = (mat == 0) ? qws : kws;
        u16x4 pk = {f2bf(a.x + b0), f2bf(a.y + b1), f2bf(a.z + b2), f2bf(a.w + b3)};
        *(u16x4*)(dst + ((size_t)((b * NH + h) * NPIX + n)) * HD + d0) = pk;
      } else {
        unsigned short* vr = vtws + ((size_t)((b * NH + h) * HD + d0)) * NPIX + n;
        vr[0] = f2bf(a.x + b0);
        vr[(size_t)NPIX] = f2bf(a.y + b1);
        vr[(size_t)2 * NPIX] = f2bf(a.z + b2);
        vr[(size_t)3 * NPIX] = f2bf(a.w + b3);
      }
    }
  }
}

// ---------------------------------------------------------------------------
// k_attn: 1D grid 800 blocks, XCD decode (R11-verified). 256 thr = 4 waves;
// wave wid owns TWO 16-q tiles (rows q0+wid*32+q, +16). NO K/V staging:
// fragments read directly from global (L2-resident), ping-pong prefetched
// one tile ahead into registers. NO __syncthreads in the loop. P round-trip
// (wave-private LDS) + lgkmcnt(0)+sched_barrier fence: verbatim R10/R15.
// Loop-end sched_barrier(0) pins P-gather (reads) before next iteration's
// P-writes (LDS ops complete in-order per wave).
// LDS: P only, 16KB (wid*4096: A@+0 2KB, B@+2048 2KB).
// ---------------------------------------------------------------------------
__global__ __launch_bounds__(256) void k_attn(
    const unsigned short* __restrict__ qws, const unsigned short* __restrict__ kws,
    const unsigned short* __restrict__ vtws, float* __restrict__ out) {
  __shared__ alignas(16) unsigned char lds[16384];
  const int bid = blockIdx.x;
  const int xcd = bid & 7, inner = bid >> 3;
  const int qt = inner % 25;
  const int bh = 8 * (inner / 25) + xcd;
  const int q0 = qt * 128;
  const int t = threadIdx.x, l = t & 63, wid = t >> 6, g = l >> 4, q = l & 15;

  const int nA = q0 + wid * 32 + q;     // q-tile A row
  const int nB = nA + 16;               // q-tile B row
  const int rowA = (nA < NPIX) ? nA : (NPIX - 1);
  const int rowB = (nB < NPIX) ? nB : (NPIX - 1);

  u32x4 quA = *(const u32x4*)(qws + ((size_t)(bh * NPIX + rowA)) * HD + g * 8);
  u32x4 quB = *(const u32x4*)(qws + ((size_t)(bh * NPIX + rowB)) * HD + g * 8);
  const bf16x8 qfA = __builtin_bit_cast(bf16x8, quA);
  const bf16x8 qfB = __builtin_bit_cast(bf16x8, quB);
  const u32x4 onesu = {0x3F803F80u, 0x3F803F80u, 0x3F803F80u, 0x3F803F80u};
  const bf16x8 onesf = __builtin_bit_cast(bf16x8, onesu);  // bf16 1.0 x8
  const f32x4 zero4 = {0.f, 0.f, 0.f, 0.f};

  f32x4 oA0 = zero4, oA1 = zero4, oB0 = zero4, oB1 = zero4;
  f32x4 sumA = zero4, sumB = zero4;

  // Direct per-lane fragment sources (composition of R14-passing chunk
  // formulas with R3-passing fragment chunk-ids):
  //   kf[jj](kt) = kws + (bh*NPIX + kt*64 + jj*16 + q)*HD + g*8
  //   vf[h][c](kt) = vtws + (bh*HD + h*16 + q)*NPIX + kt*64 + c*32 + g*8
  const unsigned short* kbase = kws + ((size_t)(bh * NPIX + q)) * HD + g * 8;
  const unsigned short* vbase = vtws + ((size_t)(bh * HD + q)) * NPIX + g * 8;

  unsigned char* const pbaseA = lds + wid * 4096;
  unsigned char* const pbaseB = pbaseA + 2048;

  u32x4 kcur[4], vcur[2][2], knxt[4], vnxt[2][2];
#pragma unroll
  for (int jj = 0; jj < 4; ++jj)
    kcur[jj] = *(const u32x4*)(kbase + (size_t)(jj * 16) * HD);
#pragma unroll
  for (int h = 0; h < 2; ++h)
#pragma unroll
    for (int c = 0; c < 2; ++c)
      vcur[h][c] = *(const u32x4*)(vbase + (size_t)(h * 16) * NPIX + c * 32);

  for (int kt = 0; kt < 49; ++kt) {
    // prefetch next tile's fragments (independent; overlaps everything below)
    if (kt < 48) {
      const size_t ko = (size_t)((kt + 1) * 64) * HD;
      const int vo = (kt + 1) * 64;
#pragma unroll
      for (int jj = 0; jj < 4; ++jj)
        knxt[jj] = *(const u32x4*)(kbase + ko + (size_t)(jj * 16) * HD);
#pragma unroll
      for (int h = 0; h < 2; ++h)
#pragma unroll
        for (int c = 0; c < 2; ++c)
          vnxt[h][c] = *(const u32x4*)(vbase + (size_t)(h * 16) * NPIX + vo + c * 32);
    }

    // QK^T for both q-tiles (K frags in registers)
    f32x4 sA[4], sB[4];
    __builtin_amdgcn_s_setprio(1);
#pragma unroll
    for (int jj = 0; jj < 4; ++jj) {
      bf16x8 kf = __builtin_bit_cast(bf16x8, kcur[jj]);
      sA[jj] = __builtin_amdgcn_mfma_f32_16x16x32_bf16(kf, qfA, zero4, 0, 0, 0);
      sB[jj] = __builtin_amdgcn_mfma_f32_16x16x32_bf16(kf, qfB, zero4, 0, 0, 0);
    }
    __builtin_amdgcn_s_setprio(0);

    // p = exp2(s); pack; write P chunks (wave-private region)
    {
      unsigned pw[8];
#pragma unroll
      for (int jj = 0; jj < 4; ++jj) {
#pragma unroll
        for (int rp = 0; rp < 2; ++rp) {
          float p0 = fast_exp2(sA[jj][2 * rp + 0]);
          float p1 = fast_exp2(sA[jj][2 * rp + 1]);
          pw[jj * 2 + rp] = cvt_pk_bf16(p0, p1);
        }
      }
      u32x4 c0 = {pw[0], pw[1], pw[2], pw[3]};
      u32x4 c1 = {pw[4], pw[5], pw[6], pw[7]};
      *(u32x4*)(pbaseA + l * 16) = c0;
      *(u32x4*)(pbaseA + 1024 + l * 16) = c1;
    }
    {
      unsigned pw[8];
#pragma unroll
      for (int jj = 0; jj < 4; ++jj) {
#pragma unroll
        for (int rp = 0; rp < 2; ++rp) {
          float p0 = fast_exp2(sB[jj][2 * rp + 0]);
          float p1 = fast_exp2(sB[jj][2 * rp + 1]);
          pw[jj * 2 + rp] = cvt_pk_bf16(p0, p1);
        }
      }
      u32x4 c0 = {pw[0], pw[1], pw[2], pw[3]};
      u32x4 c1 = {pw[4], pw[5], pw[6], pw[7]};
      *(u32x4*)(pbaseB + l * 16) = c0;
      *(u32x4*)(pbaseB + 1024 + l * 16) = c1;
    }

    // HARD ORDER: drain the P ds_writes; forbid hoisting the gathers (R7).
    asm volatile("s_waitcnt lgkmcnt(0)" ::: "memory");
    __builtin_amdgcn_sched_barrier(0);

    // PV for both q-tiles (V frags in registers) + ones column-sums
#pragma unroll
    for (int c = 0; c < 2; ++c) {
      bf16x8 v0 = __builtin_bit_cast(bf16x8, vcur[0][c]);   // d 0..15
      bf16x8 v1 = __builtin_bit_cast(bf16x8, vcur[1][c]);   // d 16..31

      const unsigned char* pA = pbaseA + c * 1024 + q * 16 + (g & 2) * 4;
      u32x2 alo = *(const u32x2*)(pA + ((2 * g) & 3) * 256);
      u32x2 ahi = *(const u32x2*)(pA + ((2 * g + 1) & 3) * 256);
      u32x4 au = {alo.x, alo.y, ahi.x, ahi.y};
      bf16x8 pfA = __builtin_bit_cast(bf16x8, au);

      const unsigned char* pB = pbaseB + c * 1024 + q * 16 + (g & 2) * 4;
      u32x2 blo = *(const u32x2*)(pB + ((2 * g) & 3) * 256);
      u32x2 bhi = *(const u32x2*)(pB + ((2 * g + 1) & 3) * 256);
      u32x4 bu = {blo.x, blo.y, bhi.x, bhi.y};
      bf16x8 pfB = __builtin_bit_cast(bf16x8, bu);

      __builtin_amdgcn_s_setprio(1);
      oA0 = __builtin_amdgcn_mfma_f32_16x16x32_bf16(v0, pfA, oA0, 0, 0, 0);
      oA1 = __builtin_amdgcn_mfma_f32_16x16x32_bf16(v1, pfA, oA1, 0, 0, 0);
      sumA = __builtin_amdgcn_mfma_f32_16x16x32_bf16(onesf, pfA, sumA, 0, 0, 0);
      oB0 = __builtin_amdgcn_mfma_f32_16x16x32_bf16(v0, pfB, oB0, 0, 0, 0);
      oB1 = __builtin_amdgcn_mfma_f32_16x16x32_bf16(v1, pfB, oB1, 0, 0, 0);
      sumB = __builtin_amdgcn_mfma_f32_16x16x32_bf16(onesf, pfB, sumB, 0, 0, 0);
      __builtin_amdgcn_s_setprio(0);
    }

    // rotate prefetched fragments into place
#pragma unroll
    for (int jj = 0; jj < 4; ++jj) kcur[jj] = knxt[jj];
#pragma unroll
    for (int h = 0; h < 2; ++h)
#pragma unroll
      for (int c = 0; c < 2; ++c) vcur[h][c] = vnxt[h][c];

    // pin order: this iteration's P-gather ds_reads stay BEFORE the next
    // iteration's P ds_writes (LDS ops complete in-order per wave).
    __builtin_amdgcn_sched_barrier(0);
  }

  // sumX[0] = full-key sum for q-column q (all rows of ones*P identical)
  if (nA < NPIX) {
    const float inv = 1.0f / sumA[0];
    float* ob = out + (size_t)(bh * HD) * NPIX + nA;
#pragma unroll
    for (int r = 0; r < 4; ++r) {
      ob[(size_t)(g * 4 + r) * NPIX] = oA0[r] * inv;
      ob[(size_t)(16 + g * 4 + r) * NPIX] = oA1[r] * inv;
    }
  }
  if (nB < NPIX) {
    const float inv = 1.0f / sumB[0];
    float* ob = out + (size_t)(bh * HD) * NPIX + nB;
#pragma unroll
    for (int r = 0; r < 4; ++r) {
      ob[(size_t)(g * 4 + r) * NPIX] = oB0[r] * inv;
      ob[(size_t)(16 + g * 4 + r) * NPIX] = oB1[r] * inv;
    }
  }
}

// ---------------------------------------------------------------------------
extern "C" void kernel_launch(void* const* d_in, const int* in_sizes, int n_in,
                              void* d_out, int out_size, void* d_ws, size_t ws_size,
                              hipStream_t stream) {
  const float* x  = (const float*)d_in[0];
  const float* wq = (const float*)d_in[1];
  const float* bq = (const float*)d_in[2];
  const float* wk = (const float*)d_in[3];
  const float* bk = (const float*)d_in[4];
  const float* wv = (const float*)d_in[5];
  const float* bv = (const float*)d_in[6];
  float* out = (float*)d_out;

  unsigned char* ws = (unsigned char*)d_ws;
  unsigned short* xbT  = (unsigned short*)(ws);             // 6,422,528 B
  unsigned short* wb   = (unsigned short*)(ws + 6422528);   //   393,216 B
  unsigned short* qws  = (unsigned short*)(ws + 6815744);   // 6,422,528 B
  unsigned short* kws  = (unsigned short*)(ws + 13238272);  // 6,422,528 B
  unsigned short* vtws = (unsigned short*)(ws + 19660800);  // 6,422,528 B

  k_xpose<<<dim3(49, 4, 4), 256, 0, stream>>>(x, xbT);
  k_wconv<<<dim3(768), 256, 0, stream>>>(wq, wk, wv, wb);
  k_proj<<<dim3(49, 12), 256, 0, stream>>>(xbT, wb, bq, bk, bv, qws, kws, vtws);
  k_attn<<<dim3(800), 256, 0, stream>>>(qws, kws, vtws, out);
}

// Round 18
// 115.382 us; speedup vs baseline: 1.5532x; 1.4452x over previous
//
#include <hip/hip_runtime.h>
#include <math.h>

// ---------------------------------------------------------------------------
// MultiHeadAttention: q/k/v = 1x1conv(x), flash attention, out [B,256,56,56] f32
// B=4, Cin=Cout=256, H=W=56 (N=3136), heads=8, hd=32.
// xbT[b][n][c] bf16 -> proj GEMM (MFMA 16x16x32 bf16) -> Q,K [bh][n][32],
// V transposed [bh][32][n] -> attn: QK^T(swapped) -> exp2 -> P via LDS -> PV.
// FINAL (R15 restoration): the measured local optimum. Session map around
// the 96us k_attn plateau -- pipeline (R13, 105), finer blocks (R14, 106),
// barrier-free private staging (R16, 161), no staging/direct global (R17,
// 149), KBLK=128 (R8/R9, broken), 32x32 & K=16 fragment conventions (R2/
// R4/R5/R12, broken) -- every perturbation regresses; VALU 49% / MFMA 22% /
// LDS ~50% / HBM 3%: balanced latency-bound design, residual slack is the
// synchronized staging drain (the documented source-level barrier-drain wall).
// Key elements: shared dbuf staging via global_load_lds (1 barrier/iter),
// 4 waves x 2 q-tiles, wave-private P round-trip with lgkmcnt(0)+
// sched_barrier fence (R7-proven), ones-MFMA lsum (R10), XCD-swizzled grid
// (R11), raw v_exp_f32 (R15). log2(e)/sqrt(32) folded into Wq/bq.
// ---------------------------------------------------------------------------

#define NB   4
#define CIN  256
#define NPIX 3136
#define NH   8
#define HD   32
#define QSC  0.25503837897544295f   /* log2(e)/sqrt(32) */

typedef float          f32x4  __attribute__((ext_vector_type(4)));
typedef short          bf16x8 __attribute__((ext_vector_type(8)));
typedef unsigned int   u32x4  __attribute__((ext_vector_type(4)));
typedef unsigned int   u32x2  __attribute__((ext_vector_type(2)));
typedef unsigned short u16x4  __attribute__((ext_vector_type(4)));

static __device__ __forceinline__ unsigned short f2bf(float f) {
  union { float f; unsigned u; } v; v.f = f;
  return (unsigned short)((v.u + 0x7fffu + ((v.u >> 16) & 1u)) >> 16);  // RTNE
}

// raw v_exp_f32: D = 2^S0 (R15-verified; scores bounded, no range handling)
static __device__ __forceinline__ float fast_exp2(float x) {
  float r;
  asm("v_exp_f32 %0, %1" : "=v"(r) : "v"(x));
  return r;
}

// pack two f32 -> one dword of 2 bf16 (order verified by R3/R7/R10 pass)
static __device__ __forceinline__ unsigned cvt_pk_bf16(float lo, float hi) {
  unsigned r;
  asm("v_cvt_pk_bf16_f32 %0, %1, %2" : "=v"(r) : "v"(lo), "v"(hi));
  return r;
}

// async global->LDS, 16B per lane. LDS dest must be wave-uniform base + lane*16.
static __device__ __forceinline__ void gload_lds16(const void* g, void* l) {
  __builtin_amdgcn_global_load_lds(
      (__attribute__((address_space(1))) const void*)g,
      (__attribute__((address_space(3))) void*)l, 16, 0, 0);
}

static __device__ __forceinline__ bf16x8 lds_frag16(const unsigned char* p) {
  u32x4 u = *(const u32x4*)p;
  return __builtin_bit_cast(bf16x8, u);
}

// ---------------------------------------------------------------------------
// k_xpose: x[b][c][n] f32 -> xbT[b][n][c] bf16.  grid (49, 4, 4), 256 thr.
// ---------------------------------------------------------------------------
__global__ __launch_bounds__(256) void k_xpose(const float* __restrict__ x,
                                               unsigned short* __restrict__ xbT) {
  __shared__ unsigned short tile[64][66];
  const int n0 = blockIdx.x * 64, c0 = blockIdx.y * 64, b = blockIdx.z;
  const int t = threadIdx.x;
  const int cl = t >> 4, nl = (t & 15) * 4;
#pragma unroll
  for (int rep = 0; rep < 4; ++rep) {
    const int c = cl + rep * 16;
    f32x4 v = *(const f32x4*)(x + ((size_t)(b * CIN + c0 + c)) * NPIX + n0 + nl);
    tile[nl + 0][c] = f2bf(v.x);
    tile[nl + 1][c] = f2bf(v.y);
    tile[nl + 2][c] = f2bf(v.z);
    tile[nl + 3][c] = f2bf(v.w);
  }
  __syncthreads();
  const int nr = t >> 2, co = (t & 3) * 16;
  unsigned pw[8];
#pragma unroll
  for (int j = 0; j < 8; ++j)
    pw[j] = (unsigned)tile[nr][co + 2 * j] | ((unsigned)tile[nr][co + 2 * j + 1] << 16);
  unsigned short* dst = xbT + ((size_t)(b * NPIX + n0 + nr)) * 256 + c0 + co;
  u32x4 lo = {pw[0], pw[1], pw[2], pw[3]};
  u32x4 hi = {pw[4], pw[5], pw[6], pw[7]};
  *(u32x4*)dst = lo;
  *(u32x4*)(dst + 8) = hi;
}

// ---------------------------------------------------------------------------
// k_wconv: wq/wk/wv f32 -> wb bf16 [mat][o][c]; wq scaled by QSC. grid 768.
// ---------------------------------------------------------------------------
__global__ __launch_bounds__(256) void k_wconv(const float* __restrict__ wq,
                                               const float* __restrict__ wk,
                                               const float* __restrict__ wv,
                                               unsigned short* __restrict__ wb) {
  const int i = blockIdx.x * 256 + threadIdx.x;   // 3*65536 total
  const int mat = i >> 16, idx = i & 65535;
  const float* w = (mat == 0) ? wq : (mat == 1 ? wk : wv);
  const float s = (mat == 0) ? QSC : 1.0f;
  wb[i] = f2bf(w[idx] * s);
}

// ---------------------------------------------------------------------------
// k_proj: per (mat,b,ntile): C[256 o][64 n] = W*XbT^T + bias.
// 4 waves; wave owns mtiles {w, w+4, w+8, w+12}; 8 K-steps of 32.
// LDS frag-major chunks staged with global_load_lds; all ds_read_b128 linear.
// Q,K -> [bh][n][32] bf16 ; V -> [bh][32][n] bf16 (pre-transposed for attn).
// grid (49, 12): y = mat*4 + b.
// ---------------------------------------------------------------------------
__global__ __launch_bounds__(256) void k_proj(
    const unsigned short* __restrict__ xbT, const unsigned short* __restrict__ wb,
    const float* __restrict__ bq, const float* __restrict__ bk,
    const float* __restrict__ bv,
    unsigned short* __restrict__ qws, unsigned short* __restrict__ kws,
    unsigned short* __restrict__ vtws) {
  __shared__ alignas(16) unsigned char lds[20480];  // W frags 16KB @0, X frags 4KB @16384
  const int b = blockIdx.y & 3, mat = blockIdx.y >> 2;
  const int n0 = blockIdx.x * 64;
  const int t = threadIdx.x, l = t & 63, wid = t >> 6, g = l >> 4, q = l & 15;
  const unsigned short* wmat = wb + mat * (256 * 256);

  f32x4 acc[4][4] = {};  // [r(mtile)][nt]

  for (int ks = 0; ks < 8; ++ks) {
#pragma unroll
    for (int r = 0; r < 4; ++r) {
      const unsigned short* src = wmat + ((wid + 4 * r) * 16 + q) * 256 + ks * 32 + g * 8;
      gload_lds16(src, lds + (r * 256 + t) * 16);
    }
    gload_lds16(xbT + ((size_t)(b * NPIX + n0 + wid * 16 + q)) * 256 + ks * 32 + g * 8,
                lds + 16384 + t * 16);
    __syncthreads();

    bf16x8 wa[4], xf[4];
#pragma unroll
    for (int r = 0; r < 4; ++r) wa[r] = lds_frag16(lds + (r * 256 + wid * 64 + l) * 16);
#pragma unroll
    for (int nt = 0; nt < 4; ++nt) xf[nt] = lds_frag16(lds + 16384 + (nt * 64 + l) * 16);
#pragma unroll
    for (int r = 0; r < 4; ++r)
#pragma unroll
      for (int nt = 0; nt < 4; ++nt)
        acc[r][nt] = __builtin_amdgcn_mfma_f32_16x16x32_bf16(wa[r], xf[nt], acc[r][nt], 0, 0, 0);
    __syncthreads();
  }

  const float* bias = (mat == 0) ? bq : (mat == 1 ? bk : bv);
  const float bsc = (mat == 0) ? QSC : 1.0f;
#pragma unroll
  for (int r = 0; r < 4; ++r) {
    const int ob = (wid + 4 * r) * 16 + g * 4;  // o = ob + reg
    const int h = ob >> 5, d0 = ob & 31;
    const float b0 = bias[ob + 0] * bsc, b1 = bias[ob + 1] * bsc;
    const float b2 = bias[ob + 2] * bsc, b3 = bias[ob + 3] * bsc;
#pragma unroll
    for (int nt = 0; nt < 4; ++nt) {
      const int n = n0 + nt * 16 + q;
      f32x4 a = acc[r][nt];
      if (mat < 2) {
        unsigned short* dst = (mat == 0) ? qws : kws;
        u16x4 pk = {f2bf(a.x + b0), f2bf(a.y + b1), f2bf(a.z + b2), f2bf(a.w + b3)};
        *(u16x4*)(dst + ((size_t)((b * NH + h) * NPIX + n)) * HD + d0) = pk;
      } else {
        unsigned short* vr = vtws + ((size_t)((b * NH + h) * HD + d0)) * NPIX + n;
        vr[0] = f2bf(a.x + b0);
        vr[(size_t)NPIX] = f2bf(a.y + b1);
        vr[(size_t)2 * NPIX] = f2bf(a.z + b2);
        vr[(size_t)3 * NPIX] = f2bf(a.w + b3);
      }
    }
  }
}

// ---------------------------------------------------------------------------
// k_attn: 1D grid 800 blocks, XCD-aware decode (R11-verified):
//   xcd = bid & 7, inner = bid >> 3, qt = inner % 25, bh = 8*(inner/25) + xcd.
// 256 thr = 4 waves; wave wid computes TWO 16-q tiles (rows q0+wid*32+q, +16).
// Internals verbatim R10/R11/R15-passing: QK^T swapped, exp2 direct, P via
// LDS with lgkmcnt(0)+sched_barrier fence, PV + ones-MFMA lsum.
// ---------------------------------------------------------------------------
__global__ __launch_bounds__(256) void k_attn(
    const unsigned short* __restrict__ qws, const unsigned short* __restrict__ kws,
    const unsigned short* __restrict__ vtws, float* __restrict__ out) {
  __shared__ alignas(16) unsigned char lds[32768];
  const int bid = blockIdx.x;
  const int xcd = bid & 7, inner = bid >> 3;
  const int qt = inner % 25;
  const int bh = 8 * (inner / 25) + xcd;
  const int q0 = qt * 128;
  const int t = threadIdx.x, l = t & 63, wid = t >> 6, g = l >> 4, q = l & 15;

  const int nA = q0 + wid * 32 + q;     // q-tile A row
  const int nB = nA + 16;               // q-tile B row
  const int rowA = (nA < NPIX) ? nA : (NPIX - 1);
  const int rowB = (nB < NPIX) ? nB : (NPIX - 1);

  u32x4 quA = *(const u32x4*)(qws + ((size_t)(bh * NPIX + rowA)) * HD + g * 8);
  u32x4 quB = *(const u32x4*)(qws + ((size_t)(bh * NPIX + rowB)) * HD + g * 8);
  const bf16x8 qfA = __builtin_bit_cast(bf16x8, quA);
  const bf16x8 qfB = __builtin_bit_cast(bf16x8, quB);
  const u32x4 onesu = {0x3F803F80u, 0x3F803F80u, 0x3F803F80u, 0x3F803F80u};
  const bf16x8 onesf = __builtin_bit_cast(bf16x8, onesu);  // bf16 1.0 x8
  const f32x4 zero4 = {0.f, 0.f, 0.f, 0.f};

  f32x4 oA0 = zero4, oA1 = zero4, oB0 = zero4, oB1 = zero4;
  f32x4 sumA = zero4, sumB = zero4;

  // staging sources (chunk id == tid) -- verbatim R3/R7/R10 mappings
  const unsigned short* ksrc = kws + ((size_t)(bh * NPIX + wid * 16 + q)) * HD + g * 8;
  const unsigned short* vsrc =
      vtws + ((size_t)(bh * HD + (wid >> 1) * 16 + q)) * NPIX + (wid & 1) * 32 + g * 8;

  unsigned char* const pbaseA = lds + 16384 + wid * 4096;
  unsigned char* const pbaseB = pbaseA + 2048;

  unsigned bofs = 0;
  gload_lds16(ksrc, lds + t * 16);
  gload_lds16(vsrc, lds + 4096 + t * 16);
  __syncthreads();

  for (int kt = 0; kt < 49; ++kt) {
    if (kt < 48) {
      gload_lds16(ksrc + (size_t)(kt + 1) * 64 * HD, lds + (bofs ^ 8192) + t * 16);
      gload_lds16(vsrc + (kt + 1) * 64, lds + (bofs ^ 8192) + 4096 + t * 16);
    }
    const unsigned char* kb = lds + bofs;
    const unsigned char* vb = lds + bofs + 4096;

    // QK^T for both q-tiles from ONE set of K fragment reads
    f32x4 sA[4], sB[4];
    __builtin_amdgcn_s_setprio(1);
#pragma unroll
    for (int jj = 0; jj < 4; ++jj) {
      bf16x8 kf = lds_frag16(kb + (jj * 64 + l) * 16);
      sA[jj] = __builtin_amdgcn_mfma_f32_16x16x32_bf16(kf, qfA, zero4, 0, 0, 0);
      sB[jj] = __builtin_amdgcn_mfma_f32_16x16x32_bf16(kf, qfB, zero4, 0, 0, 0);
    }
    __builtin_amdgcn_s_setprio(0);

    // p = exp2(s); pack; write P chunks (per-wave region)
    {
      unsigned pw[8];
#pragma unroll
      for (int jj = 0; jj < 4; ++jj) {
#pragma unroll
        for (int rp = 0; rp < 2; ++rp) {
          float p0 = fast_exp2(sA[jj][2 * rp + 0]);
          float p1 = fast_exp2(sA[jj][2 * rp + 1]);
          pw[jj * 2 + rp] = cvt_pk_bf16(p0, p1);
        }
      }
      u32x4 c0 = {pw[0], pw[1], pw[2], pw[3]};
      u32x4 c1 = {pw[4], pw[5], pw[6], pw[7]};
      *(u32x4*)(pbaseA + l * 16) = c0;
      *(u32x4*)(pbaseA + 1024 + l * 16) = c1;
    }
    {
      unsigned pw[8];
#pragma unroll
      for (int jj = 0; jj < 4; ++jj) {
#pragma unroll
        for (int rp = 0; rp < 2; ++rp) {
          float p0 = fast_exp2(sB[jj][2 * rp + 0]);
          float p1 = fast_exp2(sB[jj][2 * rp + 1]);
          pw[jj * 2 + rp] = cvt_pk_bf16(p0, p1);
        }
      }
      u32x4 c0 = {pw[0], pw[1], pw[2], pw[3]};
      u32x4 c1 = {pw[4], pw[5], pw[6], pw[7]};
      *(u32x4*)(pbaseB + l * 16) = c0;
      *(u32x4*)(pbaseB + 1024 + l * 16) = c1;
    }

    // HARD ORDER: drain the P ds_writes, and forbid the scheduler from
    // hoisting the PV gathers above this point (rule #18 pattern).
    asm volatile("s_waitcnt lgkmcnt(0)" ::: "memory");
    __builtin_amdgcn_sched_barrier(0);

    // PV for both q-tiles from ONE set of V fragment reads + ones column-sums
#pragma unroll
    for (int c = 0; c < 2; ++c) {
      bf16x8 v0 = lds_frag16(vb + (c * 64 + l) * 16);          // d 0..15
      bf16x8 v1 = lds_frag16(vb + (128 + c * 64 + l) * 16);    // d 16..31

      const unsigned char* pA = pbaseA + c * 1024 + q * 16 + (g & 2) * 4;
      u32x2 alo = *(const u32x2*)(pA + ((2 * g) & 3) * 256);
      u32x2 ahi = *(const u32x2*)(pA + ((2 * g + 1) & 3) * 256);
      u32x4 au = {alo.x, alo.y, ahi.x, ahi.y};
      bf16x8 pfA = __builtin_bit_cast(bf16x8, au);

      const unsigned char* pB = pbaseB + c * 1024 + q * 16 + (g & 2) * 4;
      u32x2 blo = *(const u32x2*)(pB + ((2 * g) & 3) * 256);
      u32x2 bhi = *(const u32x2*)(pB + ((2 * g + 1) & 3) * 256);
      u32x4 bu = {blo.x, blo.y, bhi.x, bhi.y};
      bf16x8 pfB = __builtin_bit_cast(bf16x8, bu);

      __builtin_amdgcn_s_setprio(1);
      oA0 = __builtin_amdgcn_mfma_f32_16x16x32_bf16(v0, pfA, oA0, 0, 0, 0);
      oA1 = __builtin_amdgcn_mfma_f32_16x16x32_bf16(v1, pfA, oA1, 0, 0, 0);
      sumA = __builtin_amdgcn_mfma_f32_16x16x32_bf16(onesf, pfA, sumA, 0, 0, 0);
      oB0 = __builtin_amdgcn_mfma_f32_16x16x32_bf16(v0, pfB, oB0, 0, 0, 0);
      oB1 = __builtin_amdgcn_mfma_f32_16x16x32_bf16(v1, pfB, oB1, 0, 0, 0);
      sumB = __builtin_amdgcn_mfma_f32_16x16x32_bf16(onesf, pfB, sumB, 0, 0, 0);
      __builtin_amdgcn_s_setprio(0);
    }

    __syncthreads();   // drains vmcnt + lgkm: next tile staged; reads retired
    bofs ^= 8192;
  }

  // sumX[0] = full-key sum for q-column q (all rows of ones*P identical)
  if (nA < NPIX) {
    const float inv = 1.0f / sumA[0];
    float* ob = out + (size_t)(bh * HD) * NPIX + nA;
#pragma unroll
    for (int r = 0; r < 4; ++r) {
      ob[(size_t)(g * 4 + r) * NPIX] = oA0[r] * inv;
      ob[(size_t)(16 + g * 4 + r) * NPIX] = oA1[r] * inv;
    }
  }
  if (nB < NPIX) {
    const float inv = 1.0f / sumB[0];
    float* ob = out + (size_t)(bh * HD) * NPIX + nB;
#pragma unroll
    for (int r = 0; r < 4; ++r) {
      ob[(size_t)(g * 4 + r) * NPIX] = oB0[r] * inv;
      ob[(size_t)(16 + g * 4 + r) * NPIX] = oB1[r] * inv;
    }
  }
}

// ---------------------------------------------------------------------------
extern "C" void kernel_launch(void* const* d_in, const int* in_sizes, int n_in,
                              void* d_out, int out_size, void* d_ws, size_t ws_size,
                              hipStream_t stream) {
  const float* x  = (const float*)d_in[0];
  const float* wq = (const float*)d_in[1];
  const float* bq = (const float*)d_in[2];
  const float* wk = (const float*)d_in[3];
  const float* bk = (const float*)d_in[4];
  const float* wv = (const float*)d_in[5];
  const float* bv = (const float*)d_in[6];
  float* out = (float*)d_out;

  unsigned char* ws = (unsigned char*)d_ws;
  unsigned short* xbT  = (unsigned short*)(ws);             // 6,422,528 B
  unsigned short* wb   = (unsigned short*)(ws + 6422528);   //   393,216 B
  unsigned short* qws  = (unsigned short*)(ws + 6815744);   // 6,422,528 B
  unsigned short* kws  = (unsigned short*)(ws + 13238272);  // 6,422,528 B
  unsigned short* vtws = (unsigned short*)(ws + 19660800);  // 6,422,528 B

  k_xpose<<<dim3(49, 4, 4), 256, 0, stream>>>(x, xbT);
  k_wconv<<<dim3(768), 256, 0, stream>>>(wq, wk, wv, wb);
  k_proj<<<dim3(49, 12), 256, 0, stream>>>(xbT, wb, bq, bk, bv, qws, kws, vtws);
  k_attn<<<dim3(800), 256, 0, stream>>>(qws, kws, vtws, out);
}